// Round 1
// baseline (163.967 us; speedup 1.0000x reference)
//
#include <hip/hip_runtime.h>
#include <math.h>

#define L_LEN 262144          // L = 2^18
#define NST   64
#define TPB   256
#define PI2F  6.283185307179586476925286766559f

__device__ inline float2 cmulf(float2 a, float2 b) {
    return make_float2(a.x*b.x - a.y*b.y, a.x*b.y + a.y*b.x);
}

// ---------------- in-LDS radix-2 Stockham FFT, length M, 256 threads ---------
// Data starts in b0 (natural order); returns pointer to buffer holding the
// natural-order result. sgn = -1 forward, +1 inverse (unscaled).
template<int M>
__device__ float2* lds_fft(float2* b0, float2* b1, float sgn) {
    float2* src = b0; float2* dst = b1;
    for (int Ns = 1; Ns < M; Ns <<= 1) {
        __syncthreads();
        for (int j = threadIdx.x; j < M/2; j += TPB) {
            int r = j & (Ns - 1);
            float2 a = src[j];
            float2 b = src[j + M/2];
            float ang = sgn * PI2F * ((float)r / (float)(2*Ns));
            float s, c;
            __sincosf(ang, &s, &c);
            float2 wb = make_float2(c*b.x - s*b.y, c*b.y + s*b.x);
            int idx = ((j - r) << 1) + r;          // (j/Ns)*2Ns + r
            dst[idx]      = make_float2(a.x + wb.x, a.y + wb.y);
            dst[idx + Ns] = make_float2(a.x - wb.x, a.y - wb.y);
        }
        float2* t = src; src = dst; dst = t;
    }
    __syncthreads();
    return src;
}

// ---------------- step 1: atRoots ------------------------------------------
__global__ __launch_bounds__(TPB) void atroots_kernel(
    const float* __restrict__ Lre, const float* __restrict__ Lim,
    const float* __restrict__ Pre, const float* __restrict__ Pim,
    const float* __restrict__ Bre, const float* __restrict__ Bim,
    const float* __restrict__ Cri, const float* __restrict__ logstep,
    float2* __restrict__ A)
{
    __shared__ float  sLr[NST], sLi[NST];
    __shared__ float2 sv00[NST], sv01[NST], sv10[NST], sv11[NST];
    int t = threadIdx.x;
    if (t < NST) {
        float lr = Lre[t], li = Lim[t];
        float pr = Pre[t], pi = Pim[t];
        float br = Bre[t], bi = Bim[t];
        float cr = Cri[2*t], ci = Cri[2*t+1];
        sLr[t] = lr; sLi[t] = li;
        sv00[t] = make_float2(cr*br + ci*bi, cr*bi - ci*br);   // conj(C)*B
        sv01[t] = make_float2(cr*pr + ci*pi, cr*pi - ci*pr);   // conj(C)*P
        sv10[t] = make_float2(pr*br + pi*bi, pr*bi - pi*br);   // conj(P)*B
        sv11[t] = make_float2(pr*pr + pi*pi, 0.f);             // conj(P)*P (real)
    }
    __syncthreads();

    int j = blockIdx.x * TPB + threadIdx.x;
    double step = exp((double)logstep[0]);
    double ang  = -2.0 * M_PI * (double)j / (double)L_LEN;
    double Or = cos(ang), Oi = sin(ang);
    double dr = 1.0 + Or, di = Oi;                 // 1 + Omega
    double inv = 1.0 / (dr*dr + di*di);
    double nr = 1.0 - Or, ni = -Oi;                // 1 - Omega
    double qr = (nr*dr + ni*di) * inv;             // (1-Om)/(1+Om)
    double qi = (ni*dr - nr*di) * inv;
    double twos = 2.0 / step;
    float gr = (float)(twos * qr), gi = (float)(twos * qi);
    float cr2 = (float)(2.0 * dr * inv), ci2 = (float)(-2.0 * di * inv); // c = 2/(1+Om)

    float2 k00 = make_float2(0,0), k01 = make_float2(0,0);
    float2 k10 = make_float2(0,0), k11 = make_float2(0,0);
    #pragma unroll
    for (int n = 0; n < NST; ++n) {
        float dx = gr - sLr[n];
        float dy = gi - sLi[n];
        float iv = __frcp_rn(dx*dx + dy*dy);       // overflow -> 0 (graceful)
        float rx = dx * iv, ry = -dy * iv;         // 1/(g - Lambda_n)
        float2 v;
        v = sv00[n]; k00.x += rx*v.x - ry*v.y; k00.y += rx*v.y + ry*v.x;
        v = sv01[n]; k01.x += rx*v.x - ry*v.y; k01.y += rx*v.y + ry*v.x;
        v = sv10[n]; k10.x += rx*v.x - ry*v.y; k10.y += rx*v.y + ry*v.x;
        v = sv11[n]; k11.x += rx*v.x;          k11.y += ry*v.x;
    }
    // at = c * (k00 - k01*k10/(1+k11))
    float ax = 1.f + k11.x, ay = k11.y;
    float im = 1.f / (ax*ax + ay*ay);
    float tx = k01.x*k10.x - k01.y*k10.y;
    float ty = k01.x*k10.y + k01.y*k10.x;
    float ux = (tx*ax + ty*ay) * im;
    float uy = (ty*ax - tx*ay) * im;
    float wx = k00.x - ux, wy = k00.y - uy;
    A[j] = make_float2(cr2*wx - ci2*wy, cr2*wy + ci2*wx);
}

// ---------------- four-step pass 1 -----------------------------------------
// For each n1 (block): length-M DFT over n2 of x[n1 + N1*n2], apply twiddle
// W_N^(n1*k2), store T[n1*M + k2]. sgn: -1 fwd, +1 inv.
template<int M>
__global__ __launch_bounds__(TPB) void fft_pass1(
    const float2* __restrict__ x, float2* __restrict__ T, int N1, float sgn)
{
    __shared__ float2 b0[M], b1[M];
    int n1 = blockIdx.x;
    for (int e = threadIdx.x; e < M; e += TPB) b0[e] = x[n1 + N1*e];
    float2* res = lds_fft<M>(b0, b1, sgn);
    float invN = 1.0f / (float)(N1 * M);
    for (int e = threadIdx.x; e < M; e += TPB) {
        float ang = sgn * PI2F * ((float)(n1 * e) * invN);  // n1*e < N < 2^24
        float s, c;
        __sincosf(ang, &s, &c);
        float2 r = res[e];
        T[n1*M + e] = make_float2(c*r.x - s*r.y, c*r.y + s*r.x);
    }
}

// ---------------- four-step pass 2 (N1 = 512 always) -----------------------
// For each k2 (block): length-512 DFT over n1 of T[n1*N2 + k2];
// result res[k1] is X[k2 + N2*k1].
// MODE 0: out2[idx] = res                     (raw spectrum)
// MODE 1: out2[idx] = {u[idx], res.x*scale}   (z = u + i*K, idx in [0,L))
// MODE 2: out1[idx] = res.x*scale + D*u[idx]  (final, only idx < L)
template<int MODE>
__global__ __launch_bounds__(TPB) void fft_pass2(
    const float2* __restrict__ T, float2* __restrict__ out2,
    float* __restrict__ out1, const float* __restrict__ u,
    const float* __restrict__ Dp, int N2, float sgn, float scale)
{
    __shared__ float2 b0[512], b1[512];
    const int N1 = 512;
    int k2 = blockIdx.x;
    for (int e = threadIdx.x; e < N1; e += TPB) b0[e] = T[e*N2 + k2];
    float2* res = lds_fft<512>(b0, b1, sgn);
    for (int k1 = threadIdx.x; k1 < N1; k1 += TPB) {
        int idx = k2 + N2 * k1;
        float2 r = res[k1];
        if (MODE == 0) {
            out2[idx] = r;
        } else if (MODE == 1) {
            out2[idx] = make_float2(u[idx], r.x * scale);
        } else {
            if (idx < L_LEN) out1[idx] = fmaf(Dp[0], u[idx], r.x * scale);
        }
    }
}

// ---------------- Hermitian split + spectral product -----------------------
// Z = FFT(u + iK). U = (Z[j]+conj(Z[-j]))/2, Kf = (Z[j]-conj(Z[-j]))/(2i).
// W[j] = U*Kf  (Hermitian, so ifft(W).real is the linear convolution).
__global__ __launch_bounds__(TPB) void spectral_combine(
    const float2* __restrict__ Z, float2* __restrict__ W)
{
    const int N = 2 * L_LEN;
    int j  = blockIdx.x * TPB + threadIdx.x;
    int jr = (N - j) & (N - 1);
    float2 a = Z[j];
    float2 bc = Z[jr];
    float2 b = make_float2(bc.x, -bc.y);
    float2 U  = make_float2(0.5f*(a.x + b.x), 0.5f*(a.y + b.y));
    float2 d  = make_float2(a.x - b.x, a.y - b.y);
    float2 Kf = make_float2(0.5f*d.y, -0.5f*d.x);    // d * (-0.5i)
    W[j] = cmulf(U, Kf);
}

extern "C" void kernel_launch(void* const* d_in, const int* in_sizes, int n_in,
                              void* d_out, int out_size, void* d_ws, size_t ws_size,
                              hipStream_t stream) {
    const float* u    = (const float*)d_in[0];
    const float* Lre  = (const float*)d_in[1];
    const float* Lim  = (const float*)d_in[2];
    const float* Pre  = (const float*)d_in[3];
    const float* Pim  = (const float*)d_in[4];
    const float* Bre  = (const float*)d_in[5];
    const float* Bim  = (const float*)d_in[6];
    const float* Cri  = (const float*)d_in[7];
    const float* Dp   = (const float*)d_in[8];
    const float* lstp = (const float*)d_in[9];
    float* out = (float*)d_out;

    char* ws = (char*)d_ws;                       // 12 MB used
    float2* R0 = (float2*)(ws);                   // L   complex: atRoots
    float2* R1 = (float2*)(ws + 2u*1024*1024);    // L   complex: scratch T
    float2* R2 = (float2*)(ws + 4u*1024*1024);    // 2L  complex: z / Z / T
    float2* R3 = (float2*)(ws + 8u*1024*1024);    // 2L  complex: T / W

    // z upper half = 0 (u and K are zero-padded L -> 2L)
    hipMemsetAsync(R2 + L_LEN, 0, (size_t)L_LEN * sizeof(float2), stream);

    // 1) atRoots
    atroots_kernel<<<L_LEN/TPB, TPB, 0, stream>>>(Lre,Lim,Pre,Pim,Bre,Bim,Cri,lstp,R0);

    // 2) K = real(ifft_L(atRoots)); build z = u + i*K   (L = 512*512, sgn=+1)
    fft_pass1<512><<<512, TPB, 0, stream>>>(R0, R1, 512, +1.f);
    fft_pass2<1><<<512, TPB, 0, stream>>>(R1, R2, nullptr, u, nullptr,
                                          512, +1.f, 1.0f/(float)L_LEN);

    // 3) Z = fft_2L(z)   (2L = 512*1024, sgn=-1)
    fft_pass1<1024><<<512, TPB, 0, stream>>>(R2, R3, 512, -1.f);
    fft_pass2<0><<<1024, TPB, 0, stream>>>(R3, R2, nullptr, nullptr, nullptr,
                                           1024, -1.f, 1.f);

    // 4) W = U .* Kf
    spectral_combine<<<(2*L_LEN)/TPB, TPB, 0, stream>>>(R2, R3);

    // 5) y = real(ifft_2L(W))[:L] + D*u
    fft_pass1<1024><<<512, TPB, 0, stream>>>(R3, R2, 512, +1.f);
    fft_pass2<2><<<1024, TPB, 0, stream>>>(R2, nullptr, out, u, Dp,
                                           1024, +1.f, 1.0f/(float)(2*L_LEN));
}

// Round 3
// 140.752 us; speedup vs baseline: 1.1649x; 1.1649x over previous
//
#include <hip/hip_runtime.h>
#include <math.h>

#define L_LEN  262144          // L  = 2^18
#define N2L    524288          // 2L = 2^19
#define NST    64
#define TPB    256
#define PI2F   6.2831853071795864769f
#define PIF    3.1415926535897932385f

__device__ inline float2 cmul(float2 a, float2 b) {
    return make_float2(a.x*b.x - a.y*b.y, a.x*b.y + a.y*b.x);
}

// ---- NF independent length-M FFTs in LDS, radix-4 Stockham (+ final radix-2
// when M = 2*4^k). Layout: buf[f*M + i]. 256 threads. Data starts natural
// order in b0; returns buffer holding the natural-order result.
// sgn = -1 forward, +1 inverse (unscaled).
template<int M, int NF>
__device__ float2* lds_fft_r4(float2* b0, float2* b1, float sgn) {
    float2* src = b0; float2* dst = b1;
    int Ns = 1;
    while (Ns * 4 <= M) {
        __syncthreads();
        const int NB = NF * (M / 4);
        for (int bi = threadIdx.x; bi < NB; bi += TPB) {
            int f = bi / (M / 4);
            int j = bi & (M / 4 - 1);
            int r = j & (Ns - 1);
            const float2* s = src + f * M;
            float2 x0 = s[j];
            float2 x1 = s[j +     (M/4)];
            float2 x2 = s[j + 2 * (M/4)];
            float2 x3 = s[j + 3 * (M/4)];
            float ang = sgn * PI2F * ((float)r / (float)(4 * Ns));
            float sn, cs; __sincosf(ang, &sn, &cs);
            float2 w1 = make_float2(cs, sn);
            float2 w2 = cmul(w1, w1);
            float2 w3 = cmul(w2, w1);
            x1 = cmul(x1, w1); x2 = cmul(x2, w2); x3 = cmul(x3, w3);
            float2 t0 = make_float2(x0.x + x2.x, x0.y + x2.y);
            float2 t1 = make_float2(x0.x - x2.x, x0.y - x2.y);
            float2 t2 = make_float2(x1.x + x3.x, x1.y + x3.y);
            float2 t3 = make_float2(x1.x - x3.x, x1.y - x3.y);
            float2* d = dst + f * M + ((j - r) << 2) + r;
            d[0]      = make_float2(t0.x + t2.x, t0.y + t2.y);
            d[Ns]     = make_float2(t1.x - sgn * t3.y, t1.y + sgn * t3.x);
            d[2 * Ns] = make_float2(t0.x - t2.x, t0.y - t2.y);
            d[3 * Ns] = make_float2(t1.x + sgn * t3.y, t1.y - sgn * t3.x);
        }
        float2* t = src; src = dst; dst = t;
        Ns <<= 2;
    }
    if (Ns < M) {              // final radix-2 stage, Ns == M/2, r == j
        __syncthreads();
        const int NB = NF * (M / 2);
        for (int bi = threadIdx.x; bi < NB; bi += TPB) {
            int f = bi / (M / 2);
            int j = bi & (M / 2 - 1);
            const float2* s = src + f * M;
            float2 a = s[j];
            float2 b = s[j + M / 2];
            float ang = sgn * PI2F * ((float)j / (float)M);
            float sn, cs; __sincosf(ang, &sn, &cs);
            float2 wb = make_float2(cs * b.x - sn * b.y, cs * b.y + sn * b.x);
            float2* d = dst + f * M + j;
            d[0]     = make_float2(a.x + wb.x, a.y + wb.y);
            d[M / 2] = make_float2(a.x - wb.x, a.y - wb.y);
        }
        float2* t = src; src = dst; dst = t;
    }
    __syncthreads();
    return src;
}

// ---- K1: atRoots computed inline + iFFT-L pass1 (L = 512x512), write T1 contig
__global__ __launch_bounds__(TPB) void k1_atroots_fft(
    const float* __restrict__ Lre, const float* __restrict__ Lim,
    const float* __restrict__ Pre, const float* __restrict__ Pim,
    const float* __restrict__ Bre, const float* __restrict__ Bim,
    const float* __restrict__ Cri, const float* __restrict__ lstep,
    float2* __restrict__ T1)
{
    __shared__ float2 b0[512], b1[512];
    __shared__ float  sLr[NST], sLi[NST];
    __shared__ float2 sv00[NST], sv01[NST], sv10[NST], sv11[NST];
    int t = threadIdx.x;
    if (t < NST) {
        float lr = Lre[t], li = Lim[t];
        float pr = Pre[t], pi = Pim[t];
        float br = Bre[t], bi = Bim[t];
        float cr = Cri[2*t], ci = Cri[2*t+1];
        sLr[t] = lr; sLi[t] = li;
        sv00[t] = make_float2(cr*br + ci*bi, cr*bi - ci*br);   // conj(C)*B
        sv01[t] = make_float2(cr*pr + ci*pi, cr*pi - ci*pr);   // conj(C)*P
        sv10[t] = make_float2(pr*br + pi*bi, pr*bi - pi*br);   // conj(P)*B
        sv11[t] = make_float2(pr*pr + pi*pi, 0.f);             // conj(P)*P
    }
    __syncthreads();
    int n1 = blockIdx.x;
    float G2 = 2.0f / expf(lstep[0]);
    for (int e = t; e < 512; e += TPB) {
        int j = n1 + (e << 9);
        // (1-Om)/(1+Om) = i*tan(pi j/L);  c = 1 + i*tan;  g = i*G2*tan
        float h = PIF * ((float)j * (1.0f / (float)L_LEN));
        float sn, cs; __sincosf(h, &sn, &cs);
        float tn = sn * __frcp_rn(cs);
        // pole guard: at j=L/2 the HW cos is EXACTLY 0 -> tn=inf -> inf*0=NaN.
        // Clamp keeps gi finite; the bin's k-sums cleanly underflow to 0
        // (error ~1e-6 in K, far below the bf16 floor).
        tn = fminf(fmaxf(tn, -1e7f), 1e7f);
        float gi = G2 * tn;
        float2 k00 = make_float2(0,0), k01 = make_float2(0,0);
        float2 k10 = make_float2(0,0), k11 = make_float2(0,0);
        #pragma unroll
        for (int n = 0; n < NST; ++n) {
            float dx = -sLr[n];
            float dy = gi - sLi[n];
            float iv = __frcp_rn(dx*dx + dy*dy);
            float rx = dx * iv, ry = -dy * iv;      // 1/(g - Lambda_n)
            float2 v;
            v = sv00[n]; k00.x += rx*v.x - ry*v.y; k00.y += rx*v.y + ry*v.x;
            v = sv01[n]; k01.x += rx*v.x - ry*v.y; k01.y += rx*v.y + ry*v.x;
            v = sv10[n]; k10.x += rx*v.x - ry*v.y; k10.y += rx*v.y + ry*v.x;
            v = sv11[n]; k11.x += rx*v.x;          k11.y += ry*v.x;
        }
        float ax = 1.f + k11.x, ay = k11.y;
        float im = 1.f / (ax*ax + ay*ay);
        float tx = k01.x*k10.x - k01.y*k10.y;
        float ty = k01.x*k10.y + k01.y*k10.x;
        float wx = k00.x - (tx*ax + ty*ay) * im;
        float wy = k00.y - (ty*ax - tx*ay) * im;
        b0[e] = make_float2(wx - tn*wy, wy + tn*wx);   // (1 + i*tn) * w
    }
    float2* res = lds_fft_r4<512, 1>(b0, b1, +1.f);
    const float invL = 1.0f / (float)L_LEN;
    for (int e = t; e < 512; e += TPB) {
        float ang = PI2F * ((float)(n1 * e) * invL);
        float sn, cs; __sincosf(ang, &sn, &cs);
        T1[(n1 << 9) + e] = cmul(make_float2(cs, sn), res[e]);
    }
}

// ---- K2: iFFT-L pass2 (2 columns/block) + build zT = (u, K) transposed
__global__ __launch_bounds__(TPB) void k2_ifft_pass2_z(
    const float2* __restrict__ T1, const float* __restrict__ u,
    float2* __restrict__ zT)
{
    __shared__ float2 b0[1024], b1[1024];
    int c0 = blockIdx.x << 1;
    for (int i = threadIdx.x; i < 1024; i += TPB) {
        int f = i & 1, e = i >> 1;
        b0[f * 512 + e] = T1[(e << 9) + c0 + f];
    }
    float2* res = lds_fft_r4<512, 2>(b0, b1, +1.f);
    const float invL = 1.0f / (float)L_LEN;
    for (int i = threadIdx.x; i < 1024; i += TPB) {
        int f = i >> 9, k1 = i & 511;
        int c = c0 + f;
        int idx = c + (k1 << 9);                 // time index
        zT[(c << 9) + k1] = make_float2(u[idx], res[f * 512 + k1].x * invL);
    }
}

// ---- K3: fwd-2L pass1 (2L = 512x1024), implicit zero-pad, write T2 contig
__global__ __launch_bounds__(TPB) void k3_fwd_pass1(
    const float2* __restrict__ zT, float2* __restrict__ T2)
{
    __shared__ float2 b0[1024], b1[1024];
    int n1 = blockIdx.x;
    for (int e = threadIdx.x; e < 512; e += TPB)
        b0[e] = zT[(n1 << 9) + e];
    for (int e = 512 + threadIdx.x; e < 1024; e += TPB)
        b0[e] = make_float2(0.f, 0.f);
    float2* res = lds_fft_r4<1024, 1>(b0, b1, -1.f);
    const float inv2L = 1.0f / (float)N2L;
    for (int k2 = threadIdx.x; k2 < 1024; k2 += TPB) {
        float ang = -PI2F * ((float)(n1 * k2) * inv2L);   // n1*k2 < 2^24 exact
        float sn, cs; __sincosf(ang, &sn, &cs);
        T2[(n1 << 10) + k2] = cmul(make_float2(cs, sn), res[k2]);
    }
}

// ---- K4: fwd-2L pass2 on mirror column-pair + Hermitian split + U.*Kf -> WT
__global__ __launch_bounds__(TPB) void k4_fwd_pass2_combine(
    const float2* __restrict__ T2, float2* __restrict__ WT)
{
    __shared__ float2 b0[1024], b1[1024];
    int b  = blockIdx.x;
    int cA = (b == 0) ? 0   : b;
    int cB = (b == 0) ? 512 : 1024 - b;
    for (int i = threadIdx.x; i < 1024; i += TPB) {
        int f = i >> 9, e = i & 511;
        int c = f ? cB : cA;
        b0[f * 512 + e] = T2[(e << 10) + c];
    }
    float2* res = lds_fft_r4<512, 2>(b0, b1, -1.f);
    // res[f*512+k1] = Z[c_f + 1024*k1]; mirror of (f,k1) is (mf,m)
    for (int i = threadIdx.x; i < 1024; i += TPB) {
        int f = i >> 9, k1 = i & 511;
        int c  = f ? cB : cA;
        int mf = (b == 0) ? f : 1 - f;
        int m  = (b == 0 && f == 0) ? ((512 - k1) & 511) : (511 - k1);
        float2 zp = res[f * 512 + k1];
        float2 zq = res[mf * 512 + m];
        float2 U  = make_float2(0.5f * (zp.x + zq.x), 0.5f * (zp.y - zq.y));
        float2 dd = make_float2(zp.x - zq.x, zp.y + zq.y);  // zp - conj(zq)
        float2 Kf = make_float2(0.5f * dd.y, -0.5f * dd.x); // dd * (-i/2)
        WT[(c << 9) + k1] = cmul(U, Kf);
    }
}

// ---- K5: inv-2L pass1, reads WT via two contiguous runs, write T3 contig
__global__ __launch_bounds__(TPB) void k5_inv_pass1(
    const float2* __restrict__ WT, float2* __restrict__ T3)
{
    __shared__ float2 b0[1024], b1[1024];
    int n1 = blockIdx.x;
    for (int e = threadIdx.x; e < 1024; e += TPB) {
        int col = n1 + ((e & 1) << 9);           // W[n1+512e] position in WT
        b0[e] = WT[(col << 9) + (e >> 1)];
    }
    float2* res = lds_fft_r4<1024, 1>(b0, b1, +1.f);
    const float inv2L = 1.0f / (float)N2L;
    for (int k2 = threadIdx.x; k2 < 1024; k2 += TPB) {
        float ang = PI2F * ((float)(n1 * k2) * inv2L);
        float sn, cs; __sincosf(ang, &sn, &cs);
        T3[(n1 << 10) + k2] = cmul(make_float2(cs, sn), res[k2]);
    }
}

// ---- K6: inv-2L pass2 (2 columns/block) + scale + D*u + store y
__global__ __launch_bounds__(TPB) void k6_inv_pass2_out(
    const float2* __restrict__ T3, const float* __restrict__ u,
    const float* __restrict__ Dp, float* __restrict__ out)
{
    __shared__ float2 b0[1024], b1[1024];
    int c0 = blockIdx.x << 1;
    for (int i = threadIdx.x; i < 1024; i += TPB) {
        int f = i & 1, e = i >> 1;
        b0[f * 512 + e] = T3[(e << 10) + c0 + f];
    }
    float2* res = lds_fft_r4<512, 2>(b0, b1, +1.f);
    const float inv2L = 1.0f / (float)N2L;
    float D = Dp[0];
    for (int i = threadIdx.x; i < 512; i += TPB) {   // only k1<256 lands in [0,L)
        int f = i >> 8, k1 = i & 255;
        int idx = (c0 + f) + (k1 << 10);
        out[idx] = fmaf(D, u[idx], res[f * 512 + k1].x * inv2L);
    }
}

extern "C" void kernel_launch(void* const* d_in, const int* in_sizes, int n_in,
                              void* d_out, int out_size, void* d_ws, size_t ws_size,
                              hipStream_t stream) {
    const float* u    = (const float*)d_in[0];
    const float* Lre  = (const float*)d_in[1];
    const float* Lim  = (const float*)d_in[2];
    const float* Pre  = (const float*)d_in[3];
    const float* Pim  = (const float*)d_in[4];
    const float* Bre  = (const float*)d_in[5];
    const float* Bim  = (const float*)d_in[6];
    const float* Cri  = (const float*)d_in[7];
    const float* Dp   = (const float*)d_in[8];
    const float* lstp = (const float*)d_in[9];
    float* out = (float*)d_out;

    // 12 MB workspace (same footprint round 0 validated).
    // T3 aliases [0,4MB) -- T1/zT are dead before K5 writes it.
    char* ws = (char*)d_ws;
    float2* T1 = (float2*)(ws);                    // L  complex (2 MB)
    float2* zT = (float2*)(ws + (2u << 20));       // L  complex (2 MB), transposed
    float2* T2 = (float2*)(ws + (4u << 20));       // 2L complex (4 MB)
    float2* WT = (float2*)(ws + (8u << 20));       // 2L complex (4 MB), transposed
    float2* T3 = (float2*)(ws);                    // 2L complex (4 MB), aliases T1/zT

    k1_atroots_fft      <<<512, TPB, 0, stream>>>(Lre,Lim,Pre,Pim,Bre,Bim,Cri,lstp,T1);
    k2_ifft_pass2_z     <<<256, TPB, 0, stream>>>(T1, u, zT);
    k3_fwd_pass1        <<<512, TPB, 0, stream>>>(zT, T2);
    k4_fwd_pass2_combine<<<512, TPB, 0, stream>>>(T2, WT);
    k5_inv_pass1        <<<512, TPB, 0, stream>>>(WT, T3);
    k6_inv_pass2_out    <<<512, TPB, 0, stream>>>(T3, u, Dp, out);
}